// Round 19
// baseline (683.078 us; speedup 1.0000x reference)
//
#include <hip/hip_runtime.h>
#include <hip/hip_bf16.h>
#include <math.h>

#define NN 15000
#define NE 60000
#define NB 512
#define NIF 15
#define EIF 5
#define EHID 128
#define NSTEP 6
#define EPB 128   // edges per k_msg block (4 waves x 32 edges/wave)

typedef _Float16 half8 __attribute__((ext_vector_type(8)));
typedef float floatx4 __attribute__((ext_vector_type(4)));

typedef __attribute__((address_space(3))) _Float16 lds_f16;
typedef __attribute__((address_space(1))) const _Float16 glb_f16;

__device__ __forceinline__ void gload_lds16(const _Float16* g, _Float16* l) {
  __builtin_amdgcn_global_load_lds((glb_f16*)g, (lds_f16*)l, 16, 0, 0);
}

__device__ __forceinline__ float sigmoidf_(float x) { return 1.f / (1.f + expf(-x)); }

__global__ void k_sentinel(float* out) { out[0] = 1000.0f; }

// ---- fused init: lin0 (+relu), degree, graph bounds, weight packs, the
// step-invariant edge-net hidden layer hid[E][128], and the f16 copy of out.
// w2pp: idx<528384, layout [g<1032][o<64][j<8]; g<1024: k=g*8+j, i=k>>7, h=k&127,
//       val=w2[(i*64+o)*128+h]; g>=1024: i=(g-1024)*8+j, val=b2[i*64+o].
// wgpk: 24576 f16: [(kind*2+cc)<4][o<192][r<32], val=W[o][cc*32+r] (kind0=ih,1=hh)
// wTih: 32768 f32: [k<128][g<256] = lstm_wih[g*128+k]
// wThh: 16384 f32: [k<64][g<256]  = lstm_whh[g*64+k]
// hidp: [E][128] f16 = relu(b1 + ea@w1^T), idx in [NN*64, NN*64+NE*16).
// outf16: [NN][64] f16 copy of outv.
__global__ void k_init(const float* __restrict__ x, const float* __restrict__ l0w,
                       const float* __restrict__ l0b, const int* __restrict__ tgt,
                       const int* __restrict__ batch, float* __restrict__ outv,
                       _Float16* __restrict__ outf16,
                       float* __restrict__ deg, int* __restrict__ gstart,
                       int* __restrict__ gend,
                       const float* __restrict__ ea, const float* __restrict__ w1,
                       const float* __restrict__ b1,
                       const float* __restrict__ w2, const float* __restrict__ b2,
                       const float* __restrict__ gwih, const float* __restrict__ gwhh,
                       const float* __restrict__ lwih, const float* __restrict__ lwhh,
                       _Float16* __restrict__ w2pp, _Float16* __restrict__ hidp,
                       _Float16* __restrict__ wgpk,
                       float* __restrict__ wTih, float* __restrict__ wThh) {
  int idx = blockIdx.x * 256 + threadIdx.x;
  if (idx < NN * 64) {
    int n = idx >> 6, d = idx & 63;
    float s = l0b[d];
#pragma unroll
    for (int i = 0; i < NIF; ++i) s += x[n * NIF + i] * l0w[d * NIF + i];
    float v = fmaxf(s, 0.f);
    outv[idx] = v;
    outf16[idx] = (_Float16)v;
  }
  if (idx < NE) atomicAdd(&deg[tgt[idx]], 1.0f);
  if (idx < NN) {
    int bb = batch[idx];
    atomicMin(&gstart[bb], idx);
    atomicMax(&gend[bb], idx + 1);
  }
  // ---- hid precompute ----
  {
    int ih = idx - NN * 64;
    if (ih >= 0 && ih < NE * 16) {
      int e = ih >> 4, part = ih & 15;
      float eav[EIF];
#pragma unroll
      for (int i = 0; i < EIF; ++i) eav[i] = ea[e * EIF + i];
      half8 hv;
#pragma unroll
      for (int j = 0; j < 8; ++j) {
        int h = part * 8 + j;
        float s = b1[h];
#pragma unroll
        for (int i = 0; i < EIF; ++i) s += eav[i] * w1[h * EIF + i];
        hv[j] = (_Float16)fmaxf(s, 0.f);
      }
      *(half8*)&hidp[(size_t)e * 128 + part * 8] = hv;
    }
  }
  // ---- packs ----
  if (idx < 528384) {
    int g = idx >> 9;
    int r = idx & 511;
    int o = r >> 3, j = r & 7;
    float v;
    if (g < 1024) {
      int i = g >> 4;
      int h = ((g & 15) << 3) + j;
      v = w2[(size_t)(i * 64 + o) * 128 + h];
    } else {
      int i = ((g - 1024) << 3) + j;
      v = b2[i * 64 + o];
    }
    w2pp[idx] = (_Float16)v;
  } else if (idx < 528384 + 24576) {
    int i2 = idx - 528384;
    int kc = i2 / 6144;          // (kind*2+cc)
    int rem = i2 % 6144;
    int o = rem >> 5, r = rem & 31;
    int kind = kc >> 1, cc = kc & 1;
    float v = kind ? gwhh[o * 64 + cc * 32 + r] : gwih[o * 64 + cc * 32 + r];
    wgpk[i2] = (_Float16)v;
  } else if (idx < 528384 + 24576 + 32768) {
    int i3 = idx - (528384 + 24576);
    int k = i3 >> 8, g = i3 & 255;
    wTih[i3] = lwih[g * 128 + k];
  } else if (idx < 528384 + 24576 + 32768 + 16384) {
    int i4 = idx - (528384 + 24576 + 32768);
    int k = i4 >> 8, g = i4 & 255;
    wThh[i4] = lwhh[g * 64 + k];
  }
}

// ---- fused message pass, 2-way OUTPUT-COLUMN split, LDS-staged B, hidp ----
// (R17/R18's proven kernel, VERBATIM.) blockIdx.y = oh (output col half),
// full K=8192 per block, 64 atomicAdds/edge total. Staging gathers f16 from
// outf16. Per-il B tile [hc<4][q<4][o'<32][j<8]. 2-barrier double-buffer.
__global__ __launch_bounds__(256, 4) void k_msg(
    const _Float16* __restrict__ outf16, const _Float16* __restrict__ hidp,
    const _Float16* __restrict__ w2pp, const int* __restrict__ src,
    const int* __restrict__ tgt, float* __restrict__ agg) {
  __shared__ __align__(16) _Float16 osL[EPB][72];   // full i-range 64 + pad8
  __shared__ __align__(16) _Float16 bS[2][4096];    // B tiles: 2 x 8KB (il, il+1)
  int tid = threadIdx.x;
  int e0 = blockIdx.x * EPB;
  int oh = blockIdx.y;                  // output column half

  // DMA source sub-offsets for this thread (linear LDS order)
  const int hcA = tid >> 7, qA = (tid >> 5) & 3, opA = tid & 31;
  const size_t srcA = (size_t)qA * 512 + oh * 256 + opA * 8;            // + chunk(il,hcA)*2048
  const int tB = tid + 256;
  const int hcB = tB >> 7, qB = (tB >> 5) & 3, opB = tB & 31;
  const size_t srcB = (size_t)qB * 512 + oh * 256 + opB * 8;            // + chunk(il,hcB)*2048

  // staging: 2 threads per edge, each stages 32 of the 64 i-values (f16 direct)
  int el = tid >> 1, hf = tid & 1;
  int e = e0 + el;
  bool valid = e < NE;
  int s = valid ? src[e] : 0;
  {
    const half8* op = (const half8*)(outf16 + (size_t)s * 64 + hf * 32);
    half8 p0 = op[0];
    half8 p1 = op[1];
    half8 p2 = op[2];
    half8 p3 = op[3];
    if (!valid) {
      half8 z = {(_Float16)0.f, (_Float16)0.f, (_Float16)0.f, (_Float16)0.f,
                 (_Float16)0.f, (_Float16)0.f, (_Float16)0.f, (_Float16)0.f};
      p0 = z; p1 = z; p2 = z; p3 = z;
    }
    *(half8*)&osL[el][hf * 32 + 0] = p0;
    *(half8*)&osL[el][hf * 32 + 8] = p1;
    *(half8*)&osL[el][hf * 32 + 16] = p2;
    *(half8*)&osL[el][hf * 32 + 24] = p3;
  }

  int wv = tid >> 6, lane = tid & 63;
  int l15 = lane & 15, q = lane >> 4;
  int rbase = wv * 32 + l15;

  // loop-invariant hid A-frags: FULL h-range 128 (4 frags per m)
  half8 hidf[2][4];
#pragma unroll
  for (int m = 0; m < 2; ++m) {
    int ef = e0 + rbase + m * 16;
    if (ef > NE - 1) ef = NE - 1;  // clamped: finite values, zeroed by osv=0
    const _Float16* hp = hidp + (size_t)ef * 128 + q * 8;
#pragma unroll
    for (int hc = 0; hc < 4; ++hc)
      hidf[m][hc] = *(const half8*)(hp + hc * 32);
  }

  __syncthreads();  // osL ready

  // prologue: stage B tiles il=0 and il=1 (2 x 8 KB, 2 DMA calls each)
  {
    gload_lds16(w2pp + (size_t)(0 * 4 + hcA) * 2048 + srcA, &bS[0][0] + tid * 8);
    gload_lds16(w2pp + (size_t)(0 * 4 + hcB) * 2048 + srcB, &bS[0][0] + tid * 8 + 2048);
    gload_lds16(w2pp + (size_t)(1 * 4 + hcA) * 2048 + srcA, &bS[1][0] + tid * 8);
    gload_lds16(w2pp + (size_t)(1 * 4 + hcB) * 2048 + srcB, &bS[1][0] + tid * 8 + 2048);
  }

  floatx4 acc[2][2];
#pragma unroll
  for (int m = 0; m < 2; ++m)
#pragma unroll
    for (int og = 0; og < 2; ++og) acc[m][og] = (floatx4){0.f, 0.f, 0.f, 0.f};

  const int fbase = q * 256 + l15 * 8;  // frag base: + hc*1024 + og*128

  for (int il = 0; il < 64; ++il) {
    int p = il & 1;
    _Float16 osv0 = osL[rbase][il];
    _Float16 osv1 = osL[rbase + 16][il];
    // wait for bS[p]'s DMA, then barrier -> all pieces landed
    if (il < 63) {
      asm volatile("s_waitcnt vmcnt(2)" ::: "memory");
    } else {
      asm volatile("s_waitcnt vmcnt(0)" ::: "memory");
    }
    __builtin_amdgcn_s_barrier();
    half8 fr[4][2];
    const _Float16* bb = &bS[p][0];
#pragma unroll
    for (int hc = 0; hc < 4; ++hc)
#pragma unroll
      for (int og = 0; og < 2; ++og)
        fr[hc][og] = *(const half8*)&bb[hc * 1024 + og * 128 + fbase];
    asm volatile("s_waitcnt lgkmcnt(0)" ::: "memory");
    __builtin_amdgcn_sched_barrier(0);
    __builtin_amdgcn_s_barrier();  // all waves done reading bS[p]
    if (il < 62) {                 // restage bS[p] with tile il+2
      size_t cb2 = (size_t)(il + 2) * 4;
      _Float16* ldst = &bS[p][0] + tid * 8;
      gload_lds16(w2pp + (cb2 + hcA) * 2048 + srcA, ldst);
      gload_lds16(w2pp + (cb2 + hcB) * 2048 + srcB, ldst + 2048);
    }
    half8 os0 = {osv0, osv0, osv0, osv0, osv0, osv0, osv0, osv0};
    half8 os1 = {osv1, osv1, osv1, osv1, osv1, osv1, osv1, osv1};
#pragma unroll
    for (int hc = 0; hc < 4; ++hc) {
      half8 af0 = hidf[0][hc] * os0;
      half8 af1 = hidf[1][hc] * os1;
#pragma unroll
      for (int og = 0; og < 2; ++og) {
        acc[0][og] = __builtin_amdgcn_mfma_f32_16x16x32_f16(af0, fr[hc][og], acc[0][og], 0, 0, 0);
        acc[1][og] = __builtin_amdgcn_mfma_f32_16x16x32_f16(af1, fr[hc][og], acc[1][og], 0, 0, 0);
      }
    }
  }

  // bias chunks 256 (i 0-31) and 257 (i 32-63): A = os; this block's 32 cols
#pragma unroll
  for (int ibb = 0; ibb < 2; ++ibb) {
    int cb = 256 + ibb;
    half8 af[2];
#pragma unroll
    for (int m = 0; m < 2; ++m)
      af[m] = *(const half8*)&osL[rbase + m * 16][ibb * 32 + q * 8];
#pragma unroll
    for (int og = 0; og < 2; ++og) {
      const _Float16* bp = w2pp + ((size_t)(cb * 4 + q) * 64 + oh * 32 + og * 16 + l15) * 8;
      half8 bf = *(const half8*)bp;
#pragma unroll
      for (int m = 0; m < 2; ++m)
        acc[m][og] = __builtin_amdgcn_mfma_f32_16x16x32_f16(af[m], bf, acc[m][og], 0, 0, 0);
    }
  }

  // epilogue: C/D row=(lane>>4)*4+j (edge), col= oh*32 + og*16 + l15
#pragma unroll
  for (int m = 0; m < 2; ++m) {
    int erow = e0 + wv * 32 + m * 16 + q * 4;
#pragma unroll
    for (int j = 0; j < 4; ++j) {
      int ee = erow + j;
      if (ee < NE) {
        int t = tgt[ee];
        float* ap = agg + (size_t)t * 64 + oh * 32 + l15;
        atomicAdd(ap, acc[m][0][j]);
        atomicAdd(ap + 16, acc[m][1][j]);
      }
    }
  }
}

// ---- GRU step via MFMA, d-half split: 32 nodes x 32 d-cols per block ----
// R19: blockIdx.y = dh (d-column half). 938x2 blocks double the TLP of this
// latency-bound chain (R18: 3.7 waves/CU). Each block computes gates only
// for d in [dh*32, dh*32+32): wave wv owns d = dh*32 + wv*16 + l15, gate
// tiles at gb = g3*64 + dh*32 + wv*16 (g3<3: r,z,n). aL/hF staged full
// (K needs all 64 m-cols + 64 h-cols). agg is DOUBLE-BUFFERED across steps:
// this kernel reads aggC (this step's sums) and zeroes its own d-half of
// aggN (next step's accumulator) — sibling blocks never race (in-place
// zeroing would: one block's zero vs the other's read of the same cols).
__global__ __launch_bounds__(128, 2) void k_gru(
    const float* __restrict__ aggC, float* __restrict__ aggN,
    const float* __restrict__ deg,
    const float* __restrict__ convb, const _Float16* __restrict__ wgpk,
    const float* __restrict__ bih, const float* __restrict__ bhh,
    float* __restrict__ outv, _Float16* __restrict__ outf16) {
  __shared__ __align__(16) _Float16 aL[32][136];  // K=128 + pad8
  __shared__ float hF[32][68];
  __shared__ float cbL[64];
  int tid = threadIdx.x;
  int n0 = blockIdx.x * 32;
  int dh = blockIdx.y;
  if (tid < 64) cbL[tid] = convb[tid];
  __syncthreads();

  int nl = tid >> 2, dq = (tid & 3) * 16;
  int n = n0 + nl;
  if (n < NN) {
    float dg = fmaxf(deg[n], 1.f);
    const float4* ap = (const float4*)(aggC + (size_t)n * 64 + dq);
    const float4* hp = (const float4*)(outv + (size_t)n * 64 + dq);
#pragma unroll
    for (int t = 0; t < 4; ++t) {
      float4 a = ap[t];
      float4 h = hp[t];
      int d = dq + t * 4;
      aL[nl][d + 0] = (_Float16)fmaxf(a.x / dg + cbL[d + 0], 0.f);
      aL[nl][d + 1] = (_Float16)fmaxf(a.y / dg + cbL[d + 1], 0.f);
      aL[nl][d + 2] = (_Float16)fmaxf(a.z / dg + cbL[d + 2], 0.f);
      aL[nl][d + 3] = (_Float16)fmaxf(a.w / dg + cbL[d + 3], 0.f);
      aL[nl][64 + d + 0] = (_Float16)h.x;
      aL[nl][64 + d + 1] = (_Float16)h.y;
      aL[nl][64 + d + 2] = (_Float16)h.z;
      aL[nl][64 + d + 3] = (_Float16)h.w;
      hF[nl][d + 0] = h.x; hF[nl][d + 1] = h.y;
      hF[nl][d + 2] = h.z; hF[nl][d + 3] = h.w;
    }
    if ((dq >> 5) == dh) {  // zero own d-half of next-step accumulator
      float4* az = (float4*)(aggN + (size_t)n * 64 + dq);
#pragma unroll
      for (int t = 0; t < 4; ++t) az[t] = make_float4(0.f, 0.f, 0.f, 0.f);
    }
  } else {
#pragma unroll
    for (int t = 0; t < 4; ++t) {
      int d = dq + t * 4;
#pragma unroll
      for (int u = 0; u < 4; ++u) {
        aL[nl][d + u] = (_Float16)0.f;
        aL[nl][64 + d + u] = (_Float16)0.f;
        hF[nl][d + u] = 0.f;
      }
    }
  }
  __syncthreads();

  int wv = tid >> 6, lane = tid & 63, l15 = lane & 15, qd = lane >> 4;
  floatx4 acc[2][3][2];
#pragma unroll
  for (int mt = 0; mt < 2; ++mt)
#pragma unroll
    for (int g3 = 0; g3 < 3; ++g3)
#pragma unroll
      for (int kind = 0; kind < 2; ++kind) acc[mt][g3][kind] = (floatx4){0.f, 0.f, 0.f, 0.f};

#pragma unroll
  for (int kind = 0; kind < 2; ++kind) {
#pragma unroll
    for (int cc = 0; cc < 2; ++cc) {
      half8 af[2];
#pragma unroll
      for (int mt = 0; mt < 2; ++mt)
        af[mt] = *(const half8*)&aL[mt * 16 + l15][kind * 64 + cc * 32 + qd * 8];
#pragma unroll
      for (int g3 = 0; g3 < 3; ++g3) {
        int gb = g3 * 64 + dh * 32 + wv * 16;
        half8 bf = *(const half8*)&wgpk[((size_t)(kind * 2 + cc) * 192 + gb + l15) * 32 + qd * 8];
#pragma unroll
        for (int mt = 0; mt < 2; ++mt)
          acc[mt][g3][kind] = __builtin_amdgcn_mfma_f32_16x16x32_f16(af[mt], bf, acc[mt][g3][kind], 0, 0, 0);
      }
    }
  }

  {
    int d = dh * 32 + wv * 16 + l15;
    float bir = bih[d], bhr = bhh[d];
    float biz = bih[64 + d], bhz = bhh[64 + d];
    float bin = bih[128 + d], bhn = bhh[128 + d];
#pragma unroll
    for (int mt = 0; mt < 2; ++mt) {
#pragma unroll
      for (int j = 0; j < 4; ++j) {
        int nloc = mt * 16 + qd * 4 + j;
        int nn = n0 + nloc;
        if (nn < NN) {
          float ir = acc[mt][0][0][j] + bir, hr = acc[mt][0][1][j] + bhr;
          float iz = acc[mt][1][0][j] + biz, hz = acc[mt][1][1][j] + bhz;
          float in_ = acc[mt][2][0][j] + bin, hn = acc[mt][2][1][j] + bhn;
          float r = sigmoidf_(ir + hr);
          float z = sigmoidf_(iz + hz);
          float ng = tanhf(in_ + r * hn);
          float h = hF[nloc][d];
          float hv = (1.f - z) * ng + z * h;
          outv[(size_t)nn * 64 + d] = hv;
          outf16[(size_t)nn * 64 + d] = (_Float16)hv;
        }
      }
    }
  }
}

// ---- fully fused Set2Set (6 steps) + head, one block per graph ----
// R18's LDS-staged attention kept; R19 adds ILP-4 accumulators in the LSTM
// gate loop (192-FMA serial dependency chain -> 4 independent chains,
// latency- to throughput-bound; f32 reassociation well under threshold).
#define NSMAX 128
__global__ __launch_bounds__(256) void k_s2s(
    const float* __restrict__ outv, const int* __restrict__ gstart,
    const int* __restrict__ gend, const float* __restrict__ wTih,
    const float* __restrict__ wThh, const float* __restrict__ bih,
    const float* __restrict__ bhh, const float* __restrict__ l1w,
    const float* __restrict__ l1b, const float* __restrict__ l2w,
    const float* __restrict__ l2b, float* __restrict__ y) {
  __shared__ float qL[128], hlL[64], clL[64], gL[256];
  __shared__ float mxA[4], smA[4], accA[4][64], hidL[64];
  __shared__ float oL[NSMAX][68];  // staged graph rows (64 + pad4)
  int b = blockIdx.x, tid = threadIdx.x, wv = tid >> 6, lane = tid & 63;
  int s0g = gstart[b], e0 = gend[b];
  if (s0g > e0) { s0g = 0; e0 = 0; }
  int cnt = e0 - s0g;
  bool inL = (cnt <= NSMAX);
  if (tid < 128) qL[tid] = 0.f;
  if (tid < 64) { hlL[tid] = 0.f; clL[tid] = 0.f; }
  if (inL) {  // one coalesced pass: cnt*16 float4s
    for (int idx = tid; idx < cnt * 16; idx += 256) {
      int row = idx >> 4, c = (idx & 15) * 4;
      *(float4*)&oL[row][c] = *(const float4*)(outv + (size_t)(s0g + row) * 64 + c);
    }
  }
  __syncthreads();

  for (int step = 0; step < NSTEP; ++step) {
    {  // LSTM gates, one per thread; 4-way ILP on the K-accumulation
      int g = tid;
      float s0 = 0.f, s1 = 0.f, s2 = 0.f, s3 = 0.f;
      for (int k = 0; k < 128; k += 4) {
        s0 += qL[k + 0] * wTih[(k + 0) * 256 + g];
        s1 += qL[k + 1] * wTih[(k + 1) * 256 + g];
        s2 += qL[k + 2] * wTih[(k + 2) * 256 + g];
        s3 += qL[k + 3] * wTih[(k + 3) * 256 + g];
      }
      for (int k = 0; k < 64; k += 4) {
        s0 += hlL[k + 0] * wThh[(k + 0) * 256 + g];
        s1 += hlL[k + 1] * wThh[(k + 1) * 256 + g];
        s2 += hlL[k + 2] * wThh[(k + 2) * 256 + g];
        s3 += hlL[k + 3] * wThh[(k + 3) * 256 + g];
      }
      gL[g] = bih[g] + bhh[g] + ((s0 + s1) + (s2 + s3));
    }
    __syncthreads();
    if (tid < 64) {
      float ig = gL[tid], fg = gL[64 + tid], gg = gL[128 + tid], og = gL[192 + tid];
      float c = sigmoidf_(fg) * clL[tid] + sigmoidf_(ig) * tanhf(gg);
      clL[tid] = c;
      hlL[tid] = sigmoidf_(og) * tanhf(c);
    }
    __syncthreads();
    // attention: waves split nodes strided; two passes (max, then sum/acc)
    float hd = hlL[lane];
    float mxw = -1e30f;
    for (int nn = s0g + wv; nn < e0; nn += 4) {
      float o_nd = inL ? oL[nn - s0g][lane] : outv[(size_t)nn * 64 + lane];
      float v = o_nd * hd;
#pragma unroll
      for (int off = 32; off > 0; off >>= 1) v += __shfl_xor(v, off);
      mxw = fmaxf(mxw, v);
    }
    if (lane == 0) mxA[wv] = mxw;
    __syncthreads();
    float mx = fmaxf(fmaxf(mxA[0], mxA[1]), fmaxf(mxA[2], mxA[3]));
    float sm = 0.f, ac = 0.f;
    for (int nn = s0g + wv; nn < e0; nn += 4) {
      float o_nd = inL ? oL[nn - s0g][lane] : outv[(size_t)nn * 64 + lane];
      float v = o_nd * hd;
#pragma unroll
      for (int off = 32; off > 0; off >>= 1) v += __shfl_xor(v, off);
      float ex = expf(v - mx);
      sm += ex;
      ac += ex * o_nd;
    }
    if (lane == 0) smA[wv] = sm;
    accA[wv][lane] = ac;
    __syncthreads();
    if (tid < 64) {
      float den = smA[0] + smA[1] + smA[2] + smA[3] + 1e-16f;
      float rv = (accA[0][tid] + accA[1][tid] + accA[2][tid] + accA[3][tid]) / den;
      qL[tid] = hlL[tid];
      qL[64 + tid] = rv;
    }
    __syncthreads();
  }
  // head
  if (tid < 64) {
    float s0 = l1b[tid], s1 = 0.f;
    for (int k = 0; k < 128; k += 2) {
      s0 += qL[k] * l1w[tid * 128 + k];
      s1 += qL[k + 1] * l1w[tid * 128 + k + 1];
    }
    hidL[tid] = fmaxf(s0 + s1, 0.f);
  }
  __syncthreads();
  if (tid < 12) {
    float s = l2b[tid];
    for (int k = 0; k < 64; ++k) s += hidL[k] * l2w[tid * 64 + k];
    y[b * 12 + tid] = s;
  }
}

extern "C" void kernel_launch(void* const* d_in, const int* in_sizes, int n_in,
                              void* d_out, int out_size, void* d_ws, size_t ws_size,
                              hipStream_t stream) {
  const float* x = (const float*)d_in[0];
  const float* ea = (const float*)d_in[1];
  const int* eidx = (const int*)d_in[2];
  const int* batch = (const int*)d_in[3];
  const float* lin0_w = (const float*)d_in[4];
  const float* lin0_b = (const float*)d_in[5];
  const float* en_w1 = (const float*)d_in[6];
  const float* en_b1 = (const float*)d_in[7];
  const float* en_w2 = (const float*)d_in[8];
  const float* en_b2 = (const float*)d_in[9];
  const float* conv_b = (const float*)d_in[10];
  const float* gru_wih = (const float*)d_in[11];
  const float* gru_whh = (const float*)d_in[12];
  const float* gru_bih = (const float*)d_in[13];
  const float* gru_bhh = (const float*)d_in[14];
  const float* lstm_wih = (const float*)d_in[15];
  const float* lstm_whh = (const float*)d_in[16];
  const float* lstm_bih = (const float*)d_in[17];
  const float* lstm_bhh = (const float*)d_in[18];
  const float* lin1_w = (const float*)d_in[19];
  const float* lin1_b = (const float*)d_in[20];
  const float* lin2_w = (const float*)d_in[21];
  const float* lin2_b = (const float*)d_in[22];
  const int* srcp = eidx;
  const int* tgtp = eidx + NE;

  char* ws = (char*)d_ws;
  size_t off = 0;
  auto alloc = [&](size_t bytes) {
    char* p = ws + off;
    off += (bytes + 255) & ~(size_t)255;
    return p;
  };
  _Float16* w2pp = (_Float16*)alloc((size_t)1032 * 512 * 2);  // 1.06 MB
  _Float16* hidp = (_Float16*)alloc((size_t)NE * 128 * 2);    // 15.4 MB
  _Float16* wgpk = (_Float16*)alloc((size_t)24576 * 2);
  float* wTih = (float*)alloc((size_t)32768 * 4);
  float* wThh = (float*)alloc((size_t)16384 * 4);
  float* out = (float*)alloc((size_t)NN * 64 * 4);
  _Float16* outf16 = (_Float16*)alloc((size_t)NN * 64 * 2);   // 1.9 MB
  float* aggA = (float*)alloc((size_t)NN * 64 * 4);
  float* aggB = (float*)alloc((size_t)NN * 64 * 4);
  float* deg = (float*)alloc((size_t)NN * 4);
  int* gstart = (int*)alloc((size_t)NB * 4);
  int* gend = (int*)alloc((size_t)NB * 4);
  if (off > ws_size) {
    k_sentinel<<<1, 1, 0, stream>>>((float*)d_out);
    return;
  }

  hipMemsetAsync(deg, 0, (size_t)NN * 4, stream);
  hipMemsetAsync(gstart, 0x7f, (size_t)NB * 4, stream);
  hipMemsetAsync(gend, 0, (size_t)NB * 4, stream);
  hipMemsetAsync(aggA, 0, (size_t)NN * 64 * 4, stream);

  // grid covers lin0 (NN*64) + hid (NE*16) ranges; packs fit inside lin0 range
  k_init<<<(NN * 64 + NE * 16 + 255) / 256, 256, 0, stream>>>(
      x, lin0_w, lin0_b, tgtp, batch, out, outf16, deg, gstart, gend,
      ea, en_w1, en_b1, en_w2, en_b2, gru_wih, gru_whh, lstm_wih, lstm_whh,
      w2pp, hidp, wgpk, wTih, wThh);

  for (int step = 0; step < NSTEP; ++step) {
    float* aggC = (step & 1) ? aggB : aggA;
    float* aggN = (step & 1) ? aggA : aggB;
    k_msg<<<dim3((NE + EPB - 1) / EPB, 2), 256, 0, stream>>>(outf16, hidp, w2pp,
                                                             srcp, tgtp, aggC);
    k_gru<<<dim3((NN + 31) / 32, 2), 128, 0, stream>>>(aggC, aggN, deg, conv_b,
                                                       wgpk, gru_bih, gru_bhh,
                                                       out, outf16);
  }

  k_s2s<<<NB, 256, 0, stream>>>(out, gstart, gend, wTih, wThh, lstm_bih, lstm_bhh,
                                lin1_w, lin1_b, lin2_w, lin2_b, (float*)d_out);
}

// Round 20
// 655.515 us; speedup vs baseline: 1.0420x; 1.0420x over previous
//
#include <hip/hip_runtime.h>
#include <hip/hip_bf16.h>
#include <math.h>

#define NN 15000
#define NE 60000
#define NB 512
#define NIF 15
#define EIF 5
#define EHID 128
#define NSTEP 6
#define EPB 128   // edges per k_msg block (4 waves x 32 edges/wave)

typedef _Float16 half8 __attribute__((ext_vector_type(8)));
typedef float floatx4 __attribute__((ext_vector_type(4)));

typedef __attribute__((address_space(3))) _Float16 lds_f16;
typedef __attribute__((address_space(1))) const _Float16 glb_f16;

__device__ __forceinline__ void gload_lds16(const _Float16* g, _Float16* l) {
  __builtin_amdgcn_global_load_lds((glb_f16*)g, (lds_f16*)l, 16, 0, 0);
}

__device__ __forceinline__ float sigmoidf_(float x) { return 1.f / (1.f + expf(-x)); }

__global__ void k_sentinel(float* out) { out[0] = 1000.0f; }

// ---- fused init: lin0 (+relu), degree, graph bounds, weight packs, the
// step-invariant edge-net hidden layer hid[E][128], and the f16 copy of out.
// w2pp: idx<528384, layout [g<1032][o<64][j<8]; g<1024: k=g*8+j, i=k>>7, h=k&127,
//       val=w2[(i*64+o)*128+h]; g>=1024: i=(g-1024)*8+j, val=b2[i*64+o].
// wgpk: 24576 f16: [(kind*2+cc)<4][o<192][r<32], val=W[o][cc*32+r] (kind0=ih,1=hh)
// wTih: 32768 f32: [k<128][g<256] = lstm_wih[g*128+k]
// wThh: 16384 f32: [k<64][g<256]  = lstm_whh[g*64+k]
// hidp: [E][128] f16 = relu(b1 + ea@w1^T), idx in [NN*64, NN*64+NE*16).
// outf16: [NN][64] f16 copy of outv.
__global__ void k_init(const float* __restrict__ x, const float* __restrict__ l0w,
                       const float* __restrict__ l0b, const int* __restrict__ tgt,
                       const int* __restrict__ batch, float* __restrict__ outv,
                       _Float16* __restrict__ outf16,
                       float* __restrict__ deg, int* __restrict__ gstart,
                       int* __restrict__ gend,
                       const float* __restrict__ ea, const float* __restrict__ w1,
                       const float* __restrict__ b1,
                       const float* __restrict__ w2, const float* __restrict__ b2,
                       const float* __restrict__ gwih, const float* __restrict__ gwhh,
                       const float* __restrict__ lwih, const float* __restrict__ lwhh,
                       _Float16* __restrict__ w2pp, _Float16* __restrict__ hidp,
                       _Float16* __restrict__ wgpk,
                       float* __restrict__ wTih, float* __restrict__ wThh) {
  int idx = blockIdx.x * 256 + threadIdx.x;
  if (idx < NN * 64) {
    int n = idx >> 6, d = idx & 63;
    float s = l0b[d];
#pragma unroll
    for (int i = 0; i < NIF; ++i) s += x[n * NIF + i] * l0w[d * NIF + i];
    float v = fmaxf(s, 0.f);
    outv[idx] = v;
    outf16[idx] = (_Float16)v;
  }
  if (idx < NE) atomicAdd(&deg[tgt[idx]], 1.0f);
  if (idx < NN) {
    int bb = batch[idx];
    atomicMin(&gstart[bb], idx);
    atomicMax(&gend[bb], idx + 1);
  }
  // ---- hid precompute ----
  {
    int ih = idx - NN * 64;
    if (ih >= 0 && ih < NE * 16) {
      int e = ih >> 4, part = ih & 15;
      float eav[EIF];
#pragma unroll
      for (int i = 0; i < EIF; ++i) eav[i] = ea[e * EIF + i];
      half8 hv;
#pragma unroll
      for (int j = 0; j < 8; ++j) {
        int h = part * 8 + j;
        float s = b1[h];
#pragma unroll
        for (int i = 0; i < EIF; ++i) s += eav[i] * w1[h * EIF + i];
        hv[j] = (_Float16)fmaxf(s, 0.f);
      }
      *(half8*)&hidp[(size_t)e * 128 + part * 8] = hv;
    }
  }
  // ---- packs ----
  if (idx < 528384) {
    int g = idx >> 9;
    int r = idx & 511;
    int o = r >> 3, j = r & 7;
    float v;
    if (g < 1024) {
      int i = g >> 4;
      int h = ((g & 15) << 3) + j;
      v = w2[(size_t)(i * 64 + o) * 128 + h];
    } else {
      int i = ((g - 1024) << 3) + j;
      v = b2[i * 64 + o];
    }
    w2pp[idx] = (_Float16)v;
  } else if (idx < 528384 + 24576) {
    int i2 = idx - 528384;
    int kc = i2 / 6144;          // (kind*2+cc)
    int rem = i2 % 6144;
    int o = rem >> 5, r = rem & 31;
    int kind = kc >> 1, cc = kc & 1;
    float v = kind ? gwhh[o * 64 + cc * 32 + r] : gwih[o * 64 + cc * 32 + r];
    wgpk[i2] = (_Float16)v;
  } else if (idx < 528384 + 24576 + 32768) {
    int i3 = idx - (528384 + 24576);
    int k = i3 >> 8, g = i3 & 255;
    wTih[i3] = lwih[g * 128 + k];
  } else if (idx < 528384 + 24576 + 32768 + 16384) {
    int i4 = idx - (528384 + 24576 + 32768);
    int k = i4 >> 8, g = i4 & 255;
    wThh[i4] = lwhh[g * 64 + k];
  }
}

// ---- fused message pass, 2-way OUTPUT-COLUMN split, LDS-staged B, hidp ----
// (R17/R18's proven kernel, VERBATIM.) blockIdx.y = oh (output col half),
// full K=8192 per block, 64 atomicAdds/edge total. Staging gathers f16 from
// outf16. Per-il B tile [hc<4][q<4][o'<32][j<8]. 2-barrier double-buffer.
__global__ __launch_bounds__(256, 4) void k_msg(
    const _Float16* __restrict__ outf16, const _Float16* __restrict__ hidp,
    const _Float16* __restrict__ w2pp, const int* __restrict__ src,
    const int* __restrict__ tgt, float* __restrict__ agg) {
  __shared__ __align__(16) _Float16 osL[EPB][72];   // full i-range 64 + pad8
  __shared__ __align__(16) _Float16 bS[2][4096];    // B tiles: 2 x 8KB (il, il+1)
  int tid = threadIdx.x;
  int e0 = blockIdx.x * EPB;
  int oh = blockIdx.y;                  // output column half

  // DMA source sub-offsets for this thread (linear LDS order)
  const int hcA = tid >> 7, qA = (tid >> 5) & 3, opA = tid & 31;
  const size_t srcA = (size_t)qA * 512 + oh * 256 + opA * 8;            // + chunk(il,hcA)*2048
  const int tB = tid + 256;
  const int hcB = tB >> 7, qB = (tB >> 5) & 3, opB = tB & 31;
  const size_t srcB = (size_t)qB * 512 + oh * 256 + opB * 8;            // + chunk(il,hcB)*2048

  // staging: 2 threads per edge, each stages 32 of the 64 i-values (f16 direct)
  int el = tid >> 1, hf = tid & 1;
  int e = e0 + el;
  bool valid = e < NE;
  int s = valid ? src[e] : 0;
  {
    const half8* op = (const half8*)(outf16 + (size_t)s * 64 + hf * 32);
    half8 p0 = op[0];
    half8 p1 = op[1];
    half8 p2 = op[2];
    half8 p3 = op[3];
    if (!valid) {
      half8 z = {(_Float16)0.f, (_Float16)0.f, (_Float16)0.f, (_Float16)0.f,
                 (_Float16)0.f, (_Float16)0.f, (_Float16)0.f, (_Float16)0.f};
      p0 = z; p1 = z; p2 = z; p3 = z;
    }
    *(half8*)&osL[el][hf * 32 + 0] = p0;
    *(half8*)&osL[el][hf * 32 + 8] = p1;
    *(half8*)&osL[el][hf * 32 + 16] = p2;
    *(half8*)&osL[el][hf * 32 + 24] = p3;
  }

  int wv = tid >> 6, lane = tid & 63;
  int l15 = lane & 15, q = lane >> 4;
  int rbase = wv * 32 + l15;

  // loop-invariant hid A-frags: FULL h-range 128 (4 frags per m)
  half8 hidf[2][4];
#pragma unroll
  for (int m = 0; m < 2; ++m) {
    int ef = e0 + rbase + m * 16;
    if (ef > NE - 1) ef = NE - 1;  // clamped: finite values, zeroed by osv=0
    const _Float16* hp = hidp + (size_t)ef * 128 + q * 8;
#pragma unroll
    for (int hc = 0; hc < 4; ++hc)
      hidf[m][hc] = *(const half8*)(hp + hc * 32);
  }

  __syncthreads();  // osL ready

  // prologue: stage B tiles il=0 and il=1 (2 x 8 KB, 2 DMA calls each)
  {
    gload_lds16(w2pp + (size_t)(0 * 4 + hcA) * 2048 + srcA, &bS[0][0] + tid * 8);
    gload_lds16(w2pp + (size_t)(0 * 4 + hcB) * 2048 + srcB, &bS[0][0] + tid * 8 + 2048);
    gload_lds16(w2pp + (size_t)(1 * 4 + hcA) * 2048 + srcA, &bS[1][0] + tid * 8);
    gload_lds16(w2pp + (size_t)(1 * 4 + hcB) * 2048 + srcB, &bS[1][0] + tid * 8 + 2048);
  }

  floatx4 acc[2][2];
#pragma unroll
  for (int m = 0; m < 2; ++m)
#pragma unroll
    for (int og = 0; og < 2; ++og) acc[m][og] = (floatx4){0.f, 0.f, 0.f, 0.f};

  const int fbase = q * 256 + l15 * 8;  // frag base: + hc*1024 + og*128

  for (int il = 0; il < 64; ++il) {
    int p = il & 1;
    _Float16 osv0 = osL[rbase][il];
    _Float16 osv1 = osL[rbase + 16][il];
    // wait for bS[p]'s DMA, then barrier -> all pieces landed
    if (il < 63) {
      asm volatile("s_waitcnt vmcnt(2)" ::: "memory");
    } else {
      asm volatile("s_waitcnt vmcnt(0)" ::: "memory");
    }
    __builtin_amdgcn_s_barrier();
    half8 fr[4][2];
    const _Float16* bb = &bS[p][0];
#pragma unroll
    for (int hc = 0; hc < 4; ++hc)
#pragma unroll
      for (int og = 0; og < 2; ++og)
        fr[hc][og] = *(const half8*)&bb[hc * 1024 + og * 128 + fbase];
    asm volatile("s_waitcnt lgkmcnt(0)" ::: "memory");
    __builtin_amdgcn_sched_barrier(0);
    __builtin_amdgcn_s_barrier();  // all waves done reading bS[p]
    if (il < 62) {                 // restage bS[p] with tile il+2
      size_t cb2 = (size_t)(il + 2) * 4;
      _Float16* ldst = &bS[p][0] + tid * 8;
      gload_lds16(w2pp + (cb2 + hcA) * 2048 + srcA, ldst);
      gload_lds16(w2pp + (cb2 + hcB) * 2048 + srcB, ldst + 2048);
    }
    half8 os0 = {osv0, osv0, osv0, osv0, osv0, osv0, osv0, osv0};
    half8 os1 = {osv1, osv1, osv1, osv1, osv1, osv1, osv1, osv1};
#pragma unroll
    for (int hc = 0; hc < 4; ++hc) {
      half8 af0 = hidf[0][hc] * os0;
      half8 af1 = hidf[1][hc] * os1;
#pragma unroll
      for (int og = 0; og < 2; ++og) {
        acc[0][og] = __builtin_amdgcn_mfma_f32_16x16x32_f16(af0, fr[hc][og], acc[0][og], 0, 0, 0);
        acc[1][og] = __builtin_amdgcn_mfma_f32_16x16x32_f16(af1, fr[hc][og], acc[1][og], 0, 0, 0);
      }
    }
  }

  // bias chunks 256 (i 0-31) and 257 (i 32-63): A = os; this block's 32 cols
#pragma unroll
  for (int ibb = 0; ibb < 2; ++ibb) {
    int cb = 256 + ibb;
    half8 af[2];
#pragma unroll
    for (int m = 0; m < 2; ++m)
      af[m] = *(const half8*)&osL[rbase + m * 16][ibb * 32 + q * 8];
#pragma unroll
    for (int og = 0; og < 2; ++og) {
      const _Float16* bp = w2pp + ((size_t)(cb * 4 + q) * 64 + oh * 32 + og * 16 + l15) * 8;
      half8 bf = *(const half8*)bp;
#pragma unroll
      for (int m = 0; m < 2; ++m)
        acc[m][og] = __builtin_amdgcn_mfma_f32_16x16x32_f16(af[m], bf, acc[m][og], 0, 0, 0);
    }
  }

  // epilogue: C/D row=(lane>>4)*4+j (edge), col= oh*32 + og*16 + l15
#pragma unroll
  for (int m = 0; m < 2; ++m) {
    int erow = e0 + wv * 32 + m * 16 + q * 4;
#pragma unroll
    for (int j = 0; j < 4; ++j) {
      int ee = erow + j;
      if (ee < NE) {
        int t = tgt[ee];
        float* ap = agg + (size_t)t * 64 + oh * 32 + l15;
        atomicAdd(ap, acc[m][0][j]);
        atomicAdd(ap + 16, acc[m][1][j]);
      }
    }
  }
}

// ---- GRU step via MFMA, 32 nodes/block x 128 threads (2 waves) ----
// 469 blocks (~2/CU). Wave wv owns gate tiles g=t6*2+wv; complete (r,z,n)
// triples per d-column at t6 = dd, 2+dd, 4+dd with d=(dd*2+wv)*16+l15.
// Zeroes agg in-place; also writes the f16 copy outf16 for k_msg staging.
__global__ __launch_bounds__(128, 2) void k_gru(
    float* __restrict__ agg, const float* __restrict__ deg,
    const float* __restrict__ convb, const _Float16* __restrict__ wgpk,
    const float* __restrict__ bih, const float* __restrict__ bhh,
    float* __restrict__ outv, _Float16* __restrict__ outf16) {
  __shared__ __align__(16) _Float16 aL[32][136];  // K=128 + pad8
  __shared__ float hF[32][68];
  __shared__ float cbL[64];
  int tid = threadIdx.x;
  int n0 = blockIdx.x * 32;
  if (tid < 64) cbL[tid] = convb[tid];
  __syncthreads();

  int nl = tid >> 2, dq = (tid & 3) * 16;
  int n = n0 + nl;
  if (n < NN) {
    float dg = fmaxf(deg[n], 1.f);
    const float4* ap = (const float4*)(agg + (size_t)n * 64 + dq);
    const float4* hp = (const float4*)(outv + (size_t)n * 64 + dq);
    float4* az = (float4*)(agg + (size_t)n * 64 + dq);
#pragma unroll
    for (int t = 0; t < 4; ++t) {
      float4 a = ap[t];
      float4 h = hp[t];
      int d = dq + t * 4;
      aL[nl][d + 0] = (_Float16)fmaxf(a.x / dg + cbL[d + 0], 0.f);
      aL[nl][d + 1] = (_Float16)fmaxf(a.y / dg + cbL[d + 1], 0.f);
      aL[nl][d + 2] = (_Float16)fmaxf(a.z / dg + cbL[d + 2], 0.f);
      aL[nl][d + 3] = (_Float16)fmaxf(a.w / dg + cbL[d + 3], 0.f);
      aL[nl][64 + d + 0] = (_Float16)h.x;
      aL[nl][64 + d + 1] = (_Float16)h.y;
      aL[nl][64 + d + 2] = (_Float16)h.z;
      aL[nl][64 + d + 3] = (_Float16)h.w;
      hF[nl][d + 0] = h.x; hF[nl][d + 1] = h.y;
      hF[nl][d + 2] = h.z; hF[nl][d + 3] = h.w;
      az[t] = make_float4(0.f, 0.f, 0.f, 0.f);
    }
  } else {
#pragma unroll
    for (int t = 0; t < 4; ++t) {
      int d = dq + t * 4;
#pragma unroll
      for (int u = 0; u < 4; ++u) {
        aL[nl][d + u] = (_Float16)0.f;
        aL[nl][64 + d + u] = (_Float16)0.f;
        hF[nl][d + u] = 0.f;
      }
    }
  }
  __syncthreads();

  int wv = tid >> 6, lane = tid & 63, l15 = lane & 15, qd = lane >> 4;
  floatx4 acc[2][6][2];
#pragma unroll
  for (int mt = 0; mt < 2; ++mt)
#pragma unroll
    for (int t6 = 0; t6 < 6; ++t6)
#pragma unroll
      for (int kind = 0; kind < 2; ++kind) acc[mt][t6][kind] = (floatx4){0.f, 0.f, 0.f, 0.f};

#pragma unroll
  for (int kind = 0; kind < 2; ++kind) {
#pragma unroll
    for (int cc = 0; cc < 2; ++cc) {
      half8 af[2];
#pragma unroll
      for (int mt = 0; mt < 2; ++mt)
        af[mt] = *(const half8*)&aL[mt * 16 + l15][kind * 64 + cc * 32 + qd * 8];
#pragma unroll
      for (int t6 = 0; t6 < 6; ++t6) {
        int gb = (t6 * 2 + wv) * 16;
        half8 bf = *(const half8*)&wgpk[((size_t)(kind * 2 + cc) * 192 + gb + l15) * 32 + qd * 8];
#pragma unroll
        for (int mt = 0; mt < 2; ++mt)
          acc[mt][t6][kind] = __builtin_amdgcn_mfma_f32_16x16x32_f16(af[mt], bf, acc[mt][t6][kind], 0, 0, 0);
      }
    }
  }

#pragma unroll
  for (int dd = 0; dd < 2; ++dd) {
    int d = (dd * 2 + wv) * 16 + l15;
    float bir = bih[d], bhr = bhh[d];
    float biz = bih[64 + d], bhz = bhh[64 + d];
    float bin = bih[128 + d], bhn = bhh[128 + d];
#pragma unroll
    for (int mt = 0; mt < 2; ++mt) {
#pragma unroll
      for (int j = 0; j < 4; ++j) {
        int nloc = mt * 16 + qd * 4 + j;
        int nn = n0 + nloc;
        if (nn < NN) {
          float ir = acc[mt][dd][0][j] + bir, hr = acc[mt][dd][1][j] + bhr;
          float iz = acc[mt][2 + dd][0][j] + biz, hz = acc[mt][2 + dd][1][j] + bhz;
          float in_ = acc[mt][4 + dd][0][j] + bin, hn = acc[mt][4 + dd][1][j] + bhn;
          float r = sigmoidf_(ir + hr);
          float z = sigmoidf_(iz + hz);
          float ng = tanhf(in_ + r * hn);
          float h = hF[nloc][d];
          float hv = (1.f - z) * ng + z * h;
          outv[(size_t)nn * 64 + d] = hv;
          outf16[(size_t)nn * 64 + d] = (_Float16)hv;
        }
      }
    }
  }
}

// ---- fully fused Set2Set (6 steps) + head, one block per graph ----
// R18: the graph's outv rows are staged ONCE into LDS (f32, bit-identical
// numerics) and all 6 steps x 2 attention passes read LDS instead of global.
// Graphs are ~29 nodes (max ~60); NSMAX=128 with a wave-uniform global-read
// fallback for cnt>128 keeps correctness for any batch.
#define NSMAX 128
__global__ __launch_bounds__(256) void k_s2s(
    const float* __restrict__ outv, const int* __restrict__ gstart,
    const int* __restrict__ gend, const float* __restrict__ wTih,
    const float* __restrict__ wThh, const float* __restrict__ bih,
    const float* __restrict__ bhh, const float* __restrict__ l1w,
    const float* __restrict__ l1b, const float* __restrict__ l2w,
    const float* __restrict__ l2b, float* __restrict__ y) {
  __shared__ float qL[128], hlL[64], clL[64], gL[256];
  __shared__ float mxA[4], smA[4], accA[4][64], hidL[64];
  __shared__ float oL[NSMAX][68];  // staged graph rows (64 + pad4)
  int b = blockIdx.x, tid = threadIdx.x, wv = tid >> 6, lane = tid & 63;
  int s0 = gstart[b], e0 = gend[b];
  if (s0 > e0) { s0 = 0; e0 = 0; }
  int cnt = e0 - s0;
  bool inL = (cnt <= NSMAX);
  if (tid < 128) qL[tid] = 0.f;
  if (tid < 64) { hlL[tid] = 0.f; clL[tid] = 0.f; }
  if (inL) {  // one coalesced pass: cnt*16 float4s
    for (int idx = tid; idx < cnt * 16; idx += 256) {
      int row = idx >> 4, c = (idx & 15) * 4;
      *(float4*)&oL[row][c] = *(const float4*)(outv + (size_t)(s0 + row) * 64 + c);
    }
  }
  __syncthreads();

  for (int step = 0; step < NSTEP; ++step) {
    {  // LSTM gates, one per thread (coalesced via transposed weights)
      int g = tid;
      float s = bih[g] + bhh[g];
      for (int k = 0; k < 128; ++k) s += qL[k] * wTih[k * 256 + g];
      for (int k = 0; k < 64; ++k) s += hlL[k] * wThh[k * 256 + g];
      gL[g] = s;
    }
    __syncthreads();
    if (tid < 64) {
      float ig = gL[tid], fg = gL[64 + tid], gg = gL[128 + tid], og = gL[192 + tid];
      float c = sigmoidf_(fg) * clL[tid] + sigmoidf_(ig) * tanhf(gg);
      clL[tid] = c;
      hlL[tid] = sigmoidf_(og) * tanhf(c);
    }
    __syncthreads();
    // attention: waves split nodes strided; two passes (max, then sum/acc)
    float hd = hlL[lane];
    float mxw = -1e30f;
    for (int nn = s0 + wv; nn < e0; nn += 4) {
      float o_nd = inL ? oL[nn - s0][lane] : outv[(size_t)nn * 64 + lane];
      float v = o_nd * hd;
#pragma unroll
      for (int off = 32; off > 0; off >>= 1) v += __shfl_xor(v, off);
      mxw = fmaxf(mxw, v);
    }
    if (lane == 0) mxA[wv] = mxw;
    __syncthreads();
    float mx = fmaxf(fmaxf(mxA[0], mxA[1]), fmaxf(mxA[2], mxA[3]));
    float sm = 0.f, ac = 0.f;
    for (int nn = s0 + wv; nn < e0; nn += 4) {
      float o_nd = inL ? oL[nn - s0][lane] : outv[(size_t)nn * 64 + lane];
      float v = o_nd * hd;
#pragma unroll
      for (int off = 32; off > 0; off >>= 1) v += __shfl_xor(v, off);
      float ex = expf(v - mx);
      sm += ex;
      ac += ex * o_nd;
    }
    if (lane == 0) smA[wv] = sm;
    accA[wv][lane] = ac;
    __syncthreads();
    if (tid < 64) {
      float den = smA[0] + smA[1] + smA[2] + smA[3] + 1e-16f;
      float rv = (accA[0][tid] + accA[1][tid] + accA[2][tid] + accA[3][tid]) / den;
      qL[tid] = hlL[tid];
      qL[64 + tid] = rv;
    }
    __syncthreads();
  }
  // head
  if (tid < 64) {
    float s = l1b[tid];
    for (int k = 0; k < 128; ++k) s += qL[k] * l1w[tid * 128 + k];
    hidL[tid] = fmaxf(s, 0.f);
  }
  __syncthreads();
  if (tid < 12) {
    float s = l2b[tid];
    for (int k = 0; k < 64; ++k) s += hidL[k] * l2w[tid * 64 + k];
    y[b * 12 + tid] = s;
  }
}

extern "C" void kernel_launch(void* const* d_in, const int* in_sizes, int n_in,
                              void* d_out, int out_size, void* d_ws, size_t ws_size,
                              hipStream_t stream) {
  const float* x = (const float*)d_in[0];
  const float* ea = (const float*)d_in[1];
  const int* eidx = (const int*)d_in[2];
  const int* batch = (const int*)d_in[3];
  const float* lin0_w = (const float*)d_in[4];
  const float* lin0_b = (const float*)d_in[5];
  const float* en_w1 = (const float*)d_in[6];
  const float* en_b1 = (const float*)d_in[7];
  const float* en_w2 = (const float*)d_in[8];
  const float* en_b2 = (const float*)d_in[9];
  const float* conv_b = (const float*)d_in[10];
  const float* gru_wih = (const float*)d_in[11];
  const float* gru_whh = (const float*)d_in[12];
  const float* gru_bih = (const float*)d_in[13];
  const float* gru_bhh = (const float*)d_in[14];
  const float* lstm_wih = (const float*)d_in[15];
  const float* lstm_whh = (const float*)d_in[16];
  const float* lstm_bih = (const float*)d_in[17];
  const float* lstm_bhh = (const float*)d_in[18];
  const float* lin1_w = (const float*)d_in[19];
  const float* lin1_b = (const float*)d_in[20];
  const float* lin2_w = (const float*)d_in[21];
  const float* lin2_b = (const float*)d_in[22];
  const int* srcp = eidx;
  const int* tgtp = eidx + NE;

  char* ws = (char*)d_ws;
  size_t off = 0;
  auto alloc = [&](size_t bytes) {
    char* p = ws + off;
    off += (bytes + 255) & ~(size_t)255;
    return p;
  };
  _Float16* w2pp = (_Float16*)alloc((size_t)1032 * 512 * 2);  // 1.06 MB
  _Float16* hidp = (_Float16*)alloc((size_t)NE * 128 * 2);    // 15.4 MB
  _Float16* wgpk = (_Float16*)alloc((size_t)24576 * 2);
  float* wTih = (float*)alloc((size_t)32768 * 4);
  float* wThh = (float*)alloc((size_t)16384 * 4);
  float* out = (float*)alloc((size_t)NN * 64 * 4);
  _Float16* outf16 = (_Float16*)alloc((size_t)NN * 64 * 2);   // 1.9 MB
  float* agg = (float*)alloc((size_t)NN * 64 * 4);
  float* deg = (float*)alloc((size_t)NN * 4);
  int* gstart = (int*)alloc((size_t)NB * 4);
  int* gend = (int*)alloc((size_t)NB * 4);
  if (off > ws_size) {
    k_sentinel<<<1, 1, 0, stream>>>((float*)d_out);
    return;
  }

  hipMemsetAsync(deg, 0, (size_t)NN * 4, stream);
  hipMemsetAsync(gstart, 0x7f, (size_t)NB * 4, stream);
  hipMemsetAsync(gend, 0, (size_t)NB * 4, stream);
  hipMemsetAsync(agg, 0, (size_t)NN * 64 * 4, stream);

  // grid covers lin0 (NN*64) + hid (NE*16) ranges; packs fit inside lin0 range
  k_init<<<(NN * 64 + NE * 16 + 255) / 256, 256, 0, stream>>>(
      x, lin0_w, lin0_b, tgtp, batch, out, outf16, deg, gstart, gend,
      ea, en_w1, en_b1, en_w2, en_b2, gru_wih, gru_whh, lstm_wih, lstm_whh,
      w2pp, hidp, wgpk, wTih, wThh);

  for (int step = 0; step < NSTEP; ++step) {
    k_msg<<<dim3((NE + EPB - 1) / EPB, 2), 256, 0, stream>>>(outf16, hidp, w2pp,
                                                             srcp, tgtp, agg);
    k_gru<<<(NN + 31) / 32, 128, 0, stream>>>(agg, deg, conv_b, wgpk, gru_bih,
                                              gru_bhh, out, outf16);
  }

  k_s2s<<<NB, 256, 0, stream>>>(out, gstart, gend, wTih, wThh, lstm_bih, lstm_bhh,
                                lin1_w, lin1_b, lin2_w, lin2_b, (float*)d_out);
}